// Round 4
// baseline (610.440 us; speedup 1.0000x reference)
//
#include <hip/hip_runtime.h>
#include <hip/hip_bf16.h>

#define N 8192
#define D 256

typedef __attribute__((ext_vector_type(8))) short short8;
typedef __attribute__((ext_vector_type(4))) float f32x4;
typedef unsigned short u16;

__device__ __forceinline__ float bf2f(u16 x) {
    union { unsigned int u; float f; } cv; cv.u = ((unsigned int)x) << 16; return cv.f;
}
__device__ __forceinline__ u16 f2bf(float f) {
    __hip_bfloat16 h = __float2bfloat16(f);  // RNE
    return *reinterpret_cast<u16*>(&h);
}

// ---------------------------------------------------------------------------
// K1: squared norms + bf16 casts of source/target. One wave per row.
__global__ __launch_bounds__(256) void prep_kernel(
        const float* __restrict__ src, const float* __restrict__ tgt,
        u16* __restrict__ Xb, u16* __restrict__ Yb,
        float* __restrict__ x2, float* __restrict__ y2) {
    int w = threadIdx.x >> 6, lane = threadIdx.x & 63;
    int r = blockIdx.x * 4 + w;                 // 0..16383
    const float* s; u16* ob; float* o2; int row;
    if (r < N) { s = src; ob = Xb; o2 = x2; row = r; }
    else       { s = tgt; ob = Yb; o2 = y2; row = r - N; }
    float4 v = *(const float4*)(s + (size_t)row * D + lane * 4);
    float sq = v.x * v.x + v.y * v.y + v.z * v.z + v.w * v.w;
    ushort4 st;
    st.x = f2bf(v.x); st.y = f2bf(v.y); st.z = f2bf(v.z); st.w = f2bf(v.w);
    *(ushort4*)(ob + (size_t)row * D + lane * 4) = st;
    #pragma unroll
    for (int o = 1; o < 64; o <<= 1) sq += __shfl_xor(sq, o, 64);
    if (lane == 0) o2[row] = sq;
}

// ---------------------------------------------------------------------------
// K2: K = exp(-(x2_i + y2_j - 2*X@Y^T)/eps), bf16 output.
// 64x64 block tile, 4 waves in 2x2, each wave 32x32 via 4x mfma 16x16x32.
__global__ __launch_bounds__(256) void gemm_exp_kernel(
        const u16* __restrict__ Xb, const u16* __restrict__ Yb,
        const float* __restrict__ x2, const float* __restrict__ y2,
        u16* __restrict__ Kb) {
    int tid = threadIdx.x;
    int lane = tid & 63, w = tid >> 6;
    int wr = w >> 1, wc = w & 1;
    int bx = blockIdx.x & 127, by = blockIdx.x >> 7;
    int i0 = by * 64 + wr * 32, j0 = bx * 64 + wc * 32;
    int r0 = lane & 15, khat = lane >> 4;       // khat in [0,4)

    const short8* A0 = (const short8*)(Xb + (size_t)(i0 + r0) * D + khat * 8);
    const short8* A1 = (const short8*)(Xb + (size_t)(i0 + 16 + r0) * D + khat * 8);
    const short8* B0 = (const short8*)(Yb + (size_t)(j0 + r0) * D + khat * 8);
    const short8* B1 = (const short8*)(Yb + (size_t)(j0 + 16 + r0) * D + khat * 8);

    f32x4 acc00 = {0,0,0,0}, acc01 = {0,0,0,0}, acc10 = {0,0,0,0}, acc11 = {0,0,0,0};
    #pragma unroll
    for (int kk = 0; kk < 8; ++kk) {
        short8 a0 = A0[kk * 4];                 // advance 32 elems = 4 short8
        short8 a1 = A1[kk * 4];
        short8 b0 = B0[kk * 4];
        short8 b1 = B1[kk * 4];
        acc00 = __builtin_amdgcn_mfma_f32_16x16x32_bf16(a0, b0, acc00, 0, 0, 0);
        acc01 = __builtin_amdgcn_mfma_f32_16x16x32_bf16(a0, b1, acc01, 0, 0, 0);
        acc10 = __builtin_amdgcn_mfma_f32_16x16x32_bf16(a1, b0, acc10, 0, 0, 0);
        acc11 = __builtin_amdgcn_mfma_f32_16x16x32_bf16(a1, b1, acc11, 0, 0, 0);
    }
    // C/D layout: col = lane&15, row = (lane>>4)*4 + reg   [measured m89/m91]
    float y2q0 = y2[j0 + r0];
    float y2q1 = y2[j0 + 16 + r0];
    #pragma unroll
    for (int p = 0; p < 2; ++p) {
        f32x4 aq0 = p ? acc10 : acc00;
        f32x4 aq1 = p ? acc11 : acc01;
        #pragma unroll
        for (int r = 0; r < 4; ++r) {
            int gi = i0 + p * 16 + khat * 4 + r;
            float xx = x2[gi];
            float v0 = __expf(-10.0f * (xx + y2q0 - 2.0f * aq0[r]));
            float v1 = __expf(-10.0f * (xx + y2q1 - 2.0f * aq1[r]));
            Kb[(size_t)gi * N + j0 + r0]      = f2bf(v0);
            Kb[(size_t)gi * N + j0 + 16 + r0] = f2bf(v1);
        }
    }
}

// ---------------------------------------------------------------------------
// K3: u_i = (1/n) / (rowsum(K)_i * (1/m) + 1e-8).  One wave per row.
__global__ __launch_bounds__(256) void row_u_kernel(
        const u16* __restrict__ Kb, float* __restrict__ u) {
    int w = threadIdx.x >> 6, lane = threadIdx.x & 63;
    int row = blockIdx.x * 4 + w;
    const short8* kp = (const short8*)(Kb + (size_t)row * N) + lane;
    float s = 0.f;
    #pragma unroll
    for (int t = 0; t < 16; ++t) {
        short8 kv = kp[t * 64];
        #pragma unroll
        for (int e = 0; e < 8; ++e) s += bf2f((u16)kv[e]);
    }
    #pragma unroll
    for (int o = 1; o < 64; o <<= 1) s += __shfl_xor(s, o, 64);
    if (lane == 0) u[row] = (1.0f / N) / (s * (1.0f / N) + 1e-8f);
}

// ---------------------------------------------------------------------------
// K4: partial[rb][j] = sum_{i in chunk rb} K_ij * u_i.
// 4 col-chunks x 64 row-chunks = 256 blocks; thread owns 8 consecutive cols.
__global__ __launch_bounds__(256) void col_mv_kernel(
        const u16* __restrict__ Kb, const float* __restrict__ u,
        float* __restrict__ partial) {
    int cb = blockIdx.x & 3, rb = blockIdx.x >> 2;
    int c0 = cb * 2048 + threadIdx.x * 8;
    int i0 = rb * 128;
    float acc[8] = {0,0,0,0,0,0,0,0};
    for (int i = i0; i < i0 + 128; ++i) {
        float ui = u[i];
        short8 kv = *(const short8*)(Kb + (size_t)i * N + c0);
        #pragma unroll
        for (int e = 0; e < 8; ++e) acc[e] += ui * bf2f((u16)kv[e]);
    }
    f32x4 lo = {acc[0], acc[1], acc[2], acc[3]};
    f32x4 hi = {acc[4], acc[5], acc[6], acc[7]};
    *(f32x4*)(partial + (size_t)rb * N + c0)     = lo;
    *(f32x4*)(partial + (size_t)rb * N + c0 + 4) = hi;
}

// ---------------------------------------------------------------------------
// K5: v_j = (1/m) / (sum_p partial[p][j] + 1e-8)
__global__ __launch_bounds__(256) void reduce_v_kernel(
        const float* __restrict__ partial, float* __restrict__ v) {
    int j0 = blockIdx.x * 1024 + threadIdx.x * 4;
    f32x4 s = {0,0,0,0};
    #pragma unroll 4
    for (int p = 0; p < 64; ++p) s += *(const f32x4*)(partial + (size_t)p * N + j0);
    f32x4 out;
    #pragma unroll
    for (int e = 0; e < 4; ++e) out[e] = (1.0f / N) / (s[e] + 1e-8f);
    *(f32x4*)(v + j0) = out;
}

// ---------------------------------------------------------------------------
// K6: P_ij = u_i * K_ij * v_j  (f32 out). One block per row.
__global__ __launch_bounds__(256) void final_kernel(
        const u16* __restrict__ Kb, const float* __restrict__ u,
        const float* __restrict__ v, float* __restrict__ P) {
    int row = blockIdx.x;
    float ui = u[row];
    #pragma unroll
    for (int pass = 0; pass < 4; ++pass) {
        int j = pass * 2048 + threadIdx.x * 8;
        short8 kv = *(const short8*)(Kb + (size_t)row * N + j);
        f32x4 v0 = *(const f32x4*)(v + j);
        f32x4 v1 = *(const f32x4*)(v + j + 4);
        f32x4 o0, o1;
        #pragma unroll
        for (int e = 0; e < 4; ++e) {
            o0[e] = ui * bf2f((u16)kv[e])     * v0[e];
            o1[e] = ui * bf2f((u16)kv[e + 4]) * v1[e];
        }
        *(f32x4*)(P + (size_t)row * N + j)     = o0;
        *(f32x4*)(P + (size_t)row * N + j + 4) = o1;
    }
}

// ---------------------------------------------------------------------------
extern "C" void kernel_launch(void* const* d_in, const int* in_sizes, int n_in,
                              void* d_out, int out_size, void* d_ws, size_t ws_size,
                              hipStream_t stream) {
    const float* src = (const float*)d_in[0];
    const float* tgt = (const float*)d_in[1];
    float* P = (float*)d_out;
    char* ws = (char*)d_ws;

    u16* Kb = (u16*)ws;
    size_t off = (size_t)N * N * 2;                       // 128 MB
    float* u  = (float*)(ws + off); off += (size_t)N * 4;
    float* v  = (float*)(ws + off); off += (size_t)N * 4;
    float* x2 = (float*)(ws + off); off += (size_t)N * 4;
    float* y2 = (float*)(ws + off); off += (size_t)N * 4;
    float* partial = (float*)(ws + off); off += (size_t)64 * N * 4;
    u16* Xb = (u16*)(ws + off); off += (size_t)N * D * 2;
    u16* Yb = (u16*)(ws + off); off += (size_t)N * D * 2;

    hipLaunchKernelGGL(prep_kernel,     dim3(4096),  dim3(256), 0, stream, src, tgt, Xb, Yb, x2, y2);
    hipLaunchKernelGGL(gemm_exp_kernel, dim3(16384), dim3(256), 0, stream, Xb, Yb, x2, y2, Kb);
    hipLaunchKernelGGL(row_u_kernel,    dim3(2048),  dim3(256), 0, stream, Kb, u);
    hipLaunchKernelGGL(col_mv_kernel,   dim3(256),   dim3(256), 0, stream, Kb, u, partial);
    hipLaunchKernelGGL(reduce_v_kernel, dim3(8),     dim3(256), 0, stream, partial, v);
    hipLaunchKernelGGL(final_kernel,    dim3(8192),  dim3(256), 0, stream, Kb, u, v, P);
}

// Round 5
// 462.549 us; speedup vs baseline: 1.3197x; 1.3197x over previous
//
#include <hip/hip_runtime.h>
#include <hip/hip_bf16.h>

#define N 8192
#define D 256
#define BM 128
#define BN 128
#define BK 32

typedef __attribute__((ext_vector_type(8))) short short8;
typedef __attribute__((ext_vector_type(4))) float f32x4;
typedef unsigned short u16;

__device__ __forceinline__ float bf2f(u16 x) {
    union { unsigned int u; float f; } cv; cv.u = ((unsigned int)x) << 16; return cv.f;
}
__device__ __forceinline__ u16 f2bf(float f) {
    __hip_bfloat16 h = __float2bfloat16(f);  // RNE
    return *reinterpret_cast<u16*>(&h);
}

#define GLOAD_LDS16(g, l)                                                    \
    __builtin_amdgcn_global_load_lds(                                        \
        (const __attribute__((address_space(1))) unsigned int*)(g),          \
        (__attribute__((address_space(3))) unsigned int*)(l), 16, 0, 0)

// ---------------------------------------------------------------------------
// K1: squared norms + bf16 casts of source/target. One wave per row.
__global__ __launch_bounds__(256) void prep_kernel(
        const float* __restrict__ src, const float* __restrict__ tgt,
        u16* __restrict__ Xb, u16* __restrict__ Yb,
        float* __restrict__ x2, float* __restrict__ y2) {
    int w = threadIdx.x >> 6, lane = threadIdx.x & 63;
    int r = blockIdx.x * 4 + w;                 // 0..16383
    const float* s; u16* ob; float* o2; int row;
    if (r < N) { s = src; ob = Xb; o2 = x2; row = r; }
    else       { s = tgt; ob = Yb; o2 = y2; row = r - N; }
    float4 v = *(const float4*)(s + (size_t)row * D + lane * 4);
    float sq = v.x * v.x + v.y * v.y + v.z * v.z + v.w * v.w;
    ushort4 st;
    st.x = f2bf(v.x); st.y = f2bf(v.y); st.z = f2bf(v.z); st.w = f2bf(v.w);
    *(ushort4*)(ob + (size_t)row * D + lane * 4) = st;
    #pragma unroll
    for (int o = 1; o < 64; o <<= 1) sq += __shfl_xor(sq, o, 64);
    if (lane == 0) o2[row] = sq;
}

// ---------------------------------------------------------------------------
// K2: K = exp(-(x2_i + y2_j - 2*X@Y^T)/eps) -> bf16, with fused row-sum
// atomics. m97 structure: 128x128 tile, BK=32, global_load_lds(16B) staging,
// 4 waves 2x2, each wave 64x64 via 4x4 frags of mfma 16x16x32.
__global__ __launch_bounds__(256) void gemm_exp_kernel(
        const u16* __restrict__ Xb, const u16* __restrict__ Yb,
        const float* __restrict__ x2, const float* __restrict__ y2,
        u16* __restrict__ Kb, float* __restrict__ rowsum) {
    __shared__ u16 As[BM * BK];                 // [128][32] row-major, 8KB
    __shared__ u16 Bs[BN * BK];                 // 8KB
    int tid = threadIdx.x, lane = tid & 63, w = tid >> 6;
    int wr = w >> 1, wc = w & 1;
    int bx = blockIdx.x & 63, by = blockIdx.x >> 6;
    int i0 = by * BM, j0 = bx * BN;
    int r0 = lane & 15, khat = lane >> 4;       // khat in [0,4)

    f32x4 acc[4][4] = {};

    for (int k0 = 0; k0 < D; k0 += BK) {
        // --- stage A,B tiles: chunk cid covers [row][c*8..c*8+8) of the tile.
        // LDS dest is wave-uniform base + lane*16 (linear), global src per-lane.
        #pragma unroll
        for (int s = 0; s < 2; ++s) {
            int cid = s * 256 + tid;            // 0..511
            int row = cid >> 2, c = cid & 3;
            GLOAD_LDS16(Xb + (size_t)(i0 + row) * D + k0 + c * 8,
                        As + ((size_t)(s * 256 + w * 64)) * 8);
            GLOAD_LDS16(Yb + (size_t)(j0 + row) * D + k0 + c * 8,
                        Bs + ((size_t)(s * 256 + w * 64)) * 8);
        }
        __syncthreads();                        // drain vmcnt, staging visible

        short8 af[4], bf[4];
        #pragma unroll
        for (int m = 0; m < 4; ++m)
            af[m] = *(const short8*)(As + (wr * 64 + m * 16 + r0) * BK + khat * 8);
        #pragma unroll
        for (int n = 0; n < 4; ++n)
            bf[n] = *(const short8*)(Bs + (wc * 64 + n * 16 + r0) * BK + khat * 8);
        #pragma unroll
        for (int m = 0; m < 4; ++m)
            #pragma unroll
            for (int n = 0; n < 4; ++n)
                acc[m][n] = __builtin_amdgcn_mfma_f32_16x16x32_bf16(
                    af[m], bf[n], acc[m][n], 0, 0, 0);
        __syncthreads();                        // protect LDS before overwrite
    }

    // --- epilogue: exp, bf16 store, fused row-sum (shfl over 16-lane group).
    // C/D layout: col = lane&15 (j side), row = khat*4 + reg (i side) [m89/m91]
    int iw = i0 + wr * 64, jw = j0 + wc * 64;
    float y2v[4];
    #pragma unroll
    for (int n = 0; n < 4; ++n) y2v[n] = y2[jw + n * 16 + r0];
    #pragma unroll
    for (int m = 0; m < 4; ++m) {
        #pragma unroll
        for (int r = 0; r < 4; ++r) {
            int gi = iw + m * 16 + khat * 4 + r;
            float xx = x2[gi];
            float rowpart = 0.f;
            #pragma unroll
            for (int n = 0; n < 4; ++n) {
                float val = __expf(-10.0f * (xx + y2v[n] - 2.0f * acc[m][n][r]));
                Kb[(size_t)gi * N + jw + n * 16 + r0] = f2bf(val);
                rowpart += val;
            }
            rowpart += __shfl_xor(rowpart, 1, 64);
            rowpart += __shfl_xor(rowpart, 2, 64);
            rowpart += __shfl_xor(rowpart, 4, 64);
            rowpart += __shfl_xor(rowpart, 8, 64);
            if (r0 == 0) atomicAdd(&rowsum[gi], rowpart);
        }
    }
}

// ---------------------------------------------------------------------------
// K3: u_i = (1/n) / (rowsum_i * (1/m) + 1e-8)
__global__ __launch_bounds__(256) void u_kernel(
        const float* __restrict__ rowsum, float* __restrict__ u) {
    int i = blockIdx.x * 256 + threadIdx.x;
    u[i] = (1.0f / N) / (rowsum[i] * (1.0f / N) + 1e-8f);
}

// ---------------------------------------------------------------------------
// K4: partial[rb][j] = sum_{i in 32-row chunk rb} K_ij * u_i.
// 4 col-chunks x 256 row-chunks = 1024 blocks (4 waves/SIMD).
__global__ __launch_bounds__(256) void col_mv_kernel(
        const u16* __restrict__ Kb, const float* __restrict__ u,
        float* __restrict__ partial) {
    int cb = blockIdx.x & 3, rb = blockIdx.x >> 2;
    int c0 = cb * 2048 + threadIdx.x * 8;
    int i0 = rb * 32;
    float acc[8] = {0,0,0,0,0,0,0,0};
    #pragma unroll 4
    for (int i = i0; i < i0 + 32; ++i) {
        float ui = u[i];
        short8 kv = *(const short8*)(Kb + (size_t)i * N + c0);
        #pragma unroll
        for (int e = 0; e < 8; ++e) acc[e] += ui * bf2f((u16)kv[e]);
    }
    f32x4 lo = {acc[0], acc[1], acc[2], acc[3]};
    f32x4 hi = {acc[4], acc[5], acc[6], acc[7]};
    *(f32x4*)(partial + (size_t)rb * N + c0)     = lo;
    *(f32x4*)(partial + (size_t)rb * N + c0 + 4) = hi;
}

// ---------------------------------------------------------------------------
// K5: v_j = (1/m) / (sum_p partial[p][j] + 1e-8)
__global__ __launch_bounds__(256) void reduce_v_kernel(
        const float* __restrict__ partial, float* __restrict__ v) {
    int j0 = blockIdx.x * 1024 + threadIdx.x * 4;
    f32x4 s = {0,0,0,0};
    #pragma unroll 4
    for (int p = 0; p < 256; ++p) s += *(const f32x4*)(partial + (size_t)p * N + j0);
    f32x4 out;
    #pragma unroll
    for (int e = 0; e < 4; ++e) out[e] = (1.0f / N) / (s[e] + 1e-8f);
    *(f32x4*)(v + j0) = out;
}

// ---------------------------------------------------------------------------
// K6: P_ij = u_i * K_ij * v_j  (f32 out). One block per row.
__global__ __launch_bounds__(256) void final_kernel(
        const u16* __restrict__ Kb, const float* __restrict__ u,
        const float* __restrict__ v, float* __restrict__ P) {
    int row = blockIdx.x;
    float ui = u[row];
    #pragma unroll
    for (int pass = 0; pass < 4; ++pass) {
        int j = pass * 2048 + threadIdx.x * 8;
        short8 kv = *(const short8*)(Kb + (size_t)row * N + j);
        f32x4 v0 = *(const f32x4*)(v + j);
        f32x4 v1 = *(const f32x4*)(v + j + 4);
        f32x4 o0, o1;
        #pragma unroll
        for (int e = 0; e < 4; ++e) {
            o0[e] = ui * bf2f((u16)kv[e])     * v0[e];
            o1[e] = ui * bf2f((u16)kv[e + 4]) * v1[e];
        }
        *(f32x4*)(P + (size_t)row * N + j)     = o0;
        *(f32x4*)(P + (size_t)row * N + j + 4) = o1;
    }
}

// ---------------------------------------------------------------------------
extern "C" void kernel_launch(void* const* d_in, const int* in_sizes, int n_in,
                              void* d_out, int out_size, void* d_ws, size_t ws_size,
                              hipStream_t stream) {
    const float* src = (const float*)d_in[0];
    const float* tgt = (const float*)d_in[1];
    float* P = (float*)d_out;
    char* ws = (char*)d_ws;

    u16* Kb = (u16*)ws;
    size_t off = (size_t)N * N * 2;                       // 128 MB
    float* rowsum = (float*)(ws + off); off += (size_t)N * 4;
    float* u  = (float*)(ws + off); off += (size_t)N * 4;
    float* v  = (float*)(ws + off); off += (size_t)N * 4;
    float* x2 = (float*)(ws + off); off += (size_t)N * 4;
    float* y2 = (float*)(ws + off); off += (size_t)N * 4;
    float* partial = (float*)(ws + off); off += (size_t)256 * N * 4;   // 8 MB
    u16* Xb = (u16*)(ws + off); off += (size_t)N * D * 2;
    u16* Yb = (u16*)(ws + off); off += (size_t)N * D * 2;

    hipMemsetAsync(rowsum, 0, (size_t)N * 4, stream);     // atomics accumulate
    hipLaunchKernelGGL(prep_kernel,     dim3(4096),  dim3(256), 0, stream, src, tgt, Xb, Yb, x2, y2);
    hipLaunchKernelGGL(gemm_exp_kernel, dim3(4096),  dim3(256), 0, stream, Xb, Yb, x2, y2, Kb, rowsum);
    hipLaunchKernelGGL(u_kernel,        dim3(32),    dim3(256), 0, stream, rowsum, u);
    hipLaunchKernelGGL(col_mv_kernel,   dim3(1024),  dim3(256), 0, stream, Kb, u, partial);
    hipLaunchKernelGGL(reduce_v_kernel, dim3(8),     dim3(256), 0, stream, partial, v);
    hipLaunchKernelGGL(final_kernel,    dim3(8192),  dim3(256), 0, stream, Kb, u, v, P);
}

// Round 6
// 449.495 us; speedup vs baseline: 1.3581x; 1.0290x over previous
//
#include <hip/hip_runtime.h>
#include <hip/hip_bf16.h>
#include <math.h>

#define N 8192
#define D 256
#define BM 128
#define BN 128
#define BK 64

typedef __attribute__((ext_vector_type(8))) short short8;
typedef __attribute__((ext_vector_type(4))) float f32x4;
typedef unsigned short u16;

__device__ __forceinline__ float bf2f(u16 x) {
    union { unsigned int u; float f; } cv; cv.u = ((unsigned int)x) << 16; return cv.f;
}
__device__ __forceinline__ u16 f2bf(float f) {
    __hip_bfloat16 h = __float2bfloat16(f);  // RNE
    return *reinterpret_cast<u16*>(&h);
}
__device__ __forceinline__ float u_from_rowsum(float rs) {
    return (1.0f / N) / (rs * (1.0f / N) + 1e-8f);
}

#define GLOAD_LDS16(g, l)                                                    \
    __builtin_amdgcn_global_load_lds(                                        \
        (const __attribute__((address_space(1))) unsigned int*)(g),          \
        (__attribute__((address_space(3))) unsigned int*)(l), 16, 0, 0)

// -log2(e)/epsilon and 2*log2(e)/epsilon:  exp(-10*C) == exp2(-14.4269504*C)
#define NL2E 14.42695040888963f

// ---------------------------------------------------------------------------
// K1: squared norms + bf16 casts of source/target. One wave per row.
__global__ __launch_bounds__(256) void prep_kernel(
        const float* __restrict__ src, const float* __restrict__ tgt,
        u16* __restrict__ Xb, u16* __restrict__ Yb,
        float* __restrict__ x2, float* __restrict__ y2) {
    int w = threadIdx.x >> 6, lane = threadIdx.x & 63;
    int r = blockIdx.x * 4 + w;                 // 0..16383
    const float* s; u16* ob; float* o2; int row;
    if (r < N) { s = src; ob = Xb; o2 = x2; row = r; }
    else       { s = tgt; ob = Yb; o2 = y2; row = r - N; }
    float4 v = *(const float4*)(s + (size_t)row * D + lane * 4);
    float sq = v.x * v.x + v.y * v.y + v.z * v.z + v.w * v.w;
    ushort4 st;
    st.x = f2bf(v.x); st.y = f2bf(v.y); st.z = f2bf(v.z); st.w = f2bf(v.w);
    *(ushort4*)(ob + (size_t)row * D + lane * 4) = st;
    #pragma unroll
    for (int o = 1; o < 64; o <<= 1) sq += __shfl_xor(sq, o, 64);
    if (lane == 0) o2[row] = sq;
}

// ---------------------------------------------------------------------------
// K2: K = exp(-(x2_i + y2_j - 2*X@Y^T)/eps) -> bf16, fused row-sum atomics.
// m97 structure: 128x128 tile, BK=64, global_load_lds(16B), 4 waves 2x2,
// each wave 64x64 via 4x4 frags of mfma 16x16x32 (2 k-slices per K-step).
__global__ __launch_bounds__(256) void gemm_exp_kernel(
        const u16* __restrict__ Xb, const u16* __restrict__ Yb,
        const float* __restrict__ x2, const float* __restrict__ y2,
        u16* __restrict__ Kb, float* __restrict__ rowsum) {
    __shared__ u16 As[BM * BK];                 // [128][64] row-major, 16KB
    __shared__ u16 Bs[BN * BK];                 // 16KB
    int tid = threadIdx.x, lane = tid & 63, w = tid >> 6;
    int wr = w >> 1, wc = w & 1;
    int bx = blockIdx.x & 63, by = blockIdx.x >> 6;
    int i0 = by * BM, j0 = bx * BN;
    int r0 = lane & 15, khat = lane >> 4;       // khat in [0,4)

    f32x4 acc[4][4] = {};

    for (int k0 = 0; k0 < D; k0 += BK) {
        // stage: 1024 16B-chunks per matrix; chunk = q*256 + tid;
        // row = chunk>>3, col8 = chunk&7. LDS dest linear (wave-uniform base
        // + lane*16 per m104); global src per-lane.
        #pragma unroll
        for (int q = 0; q < 4; ++q) {
            int chunk = q * 256 + tid;
            int row = chunk >> 3, c = chunk & 7;
            GLOAD_LDS16(Xb + (size_t)(i0 + row) * D + k0 + c * 8,
                        As + ((size_t)(q * 256 + w * 64)) * 8);
            GLOAD_LDS16(Yb + (size_t)(j0 + row) * D + k0 + c * 8,
                        Bs + ((size_t)(q * 256 + w * 64)) * 8);
        }
        __syncthreads();                        // drains vmcnt; staging visible

        short8 af[4][2], bf[4][2];
        #pragma unroll
        for (int m = 0; m < 4; ++m)
            #pragma unroll
            for (int kk = 0; kk < 2; ++kk)
                af[m][kk] = *(const short8*)(As + (wr * 64 + m * 16 + r0) * BK + kk * 32 + khat * 8);
        #pragma unroll
        for (int n = 0; n < 4; ++n)
            #pragma unroll
            for (int kk = 0; kk < 2; ++kk)
                bf[n][kk] = *(const short8*)(Bs + (wc * 64 + n * 16 + r0) * BK + kk * 32 + khat * 8);
        #pragma unroll
        for (int kk = 0; kk < 2; ++kk)
            #pragma unroll
            for (int m = 0; m < 4; ++m)
                #pragma unroll
                for (int n = 0; n < 4; ++n)
                    acc[m][n] = __builtin_amdgcn_mfma_f32_16x16x32_bf16(
                        af[m][kk], bf[n][kk], acc[m][n], 0, 0, 0);
        __syncthreads();                        // protect LDS before overwrite
    }

    // epilogue: K_ij = exp2(fma(2*NL2E, dot, -NL2E*(x2+y2))); bf16 store +
    // fused row-sum. C/D layout: col = lane&15, row = khat*4+reg [m89/m91]
    int iw = i0 + wr * 64, jw = j0 + wc * 64;
    float cn[4];
    #pragma unroll
    for (int n = 0; n < 4; ++n) cn[n] = -NL2E * y2[jw + n * 16 + r0];
    #pragma unroll
    for (int m = 0; m < 4; ++m) {
        #pragma unroll
        for (int r = 0; r < 4; ++r) {
            int gi = iw + m * 16 + khat * 4 + r;
            float cr = -NL2E * x2[gi];
            float rowpart = 0.f;
            #pragma unroll
            for (int n = 0; n < 4; ++n) {
                float val = exp2f(fmaf(2.0f * NL2E, acc[m][n][r], cr + cn[n]));
                Kb[(size_t)gi * N + jw + n * 16 + r0] = f2bf(val);
                rowpart += val;
            }
            rowpart += __shfl_xor(rowpart, 1, 64);
            rowpart += __shfl_xor(rowpart, 2, 64);
            rowpart += __shfl_xor(rowpart, 4, 64);
            rowpart += __shfl_xor(rowpart, 8, 64);
            if (r0 == 0) atomicAdd(&rowsum[gi], rowpart);
        }
    }
}

// ---------------------------------------------------------------------------
// K4: partial[rb][j] = sum_{i in 32-row chunk rb} K_ij * u_i, u from rowsum.
// 4 col-chunks x 256 row-chunks = 1024 blocks.
__global__ __launch_bounds__(256) void col_mv_kernel(
        const u16* __restrict__ Kb, const float* __restrict__ rowsum,
        float* __restrict__ partial) {
    int cb = blockIdx.x & 3, rb = blockIdx.x >> 2;
    int c0 = cb * 2048 + threadIdx.x * 8;
    int i0 = rb * 32;
    float acc[8] = {0,0,0,0,0,0,0,0};
    #pragma unroll 4
    for (int i = i0; i < i0 + 32; ++i) {
        float ui = u_from_rowsum(rowsum[i]);
        short8 kv = *(const short8*)(Kb + (size_t)i * N + c0);
        #pragma unroll
        for (int e = 0; e < 8; ++e) acc[e] += ui * bf2f((u16)kv[e]);
    }
    f32x4 lo = {acc[0], acc[1], acc[2], acc[3]};
    f32x4 hi = {acc[4], acc[5], acc[6], acc[7]};
    *(f32x4*)(partial + (size_t)rb * N + c0)     = lo;
    *(f32x4*)(partial + (size_t)rb * N + c0 + 4) = hi;
}

// ---------------------------------------------------------------------------
// K5: v_j = (1/m) / (sum_p partial[p][j] + 1e-8).  32 blocks, 1 col/thread.
__global__ __launch_bounds__(256) void reduce_v_kernel(
        const float* __restrict__ partial, float* __restrict__ v) {
    int j = blockIdx.x * 256 + threadIdx.x;
    float s = 0.f;
    #pragma unroll 8
    for (int p = 0; p < 256; ++p) s += partial[(size_t)p * N + j];
    v[j] = (1.0f / N) / (s + 1e-8f);
}

// ---------------------------------------------------------------------------
// K6: P_ij = u_i * K_ij * v_j  (f32 out). One block per row; u from rowsum.
__global__ __launch_bounds__(256) void final_kernel(
        const u16* __restrict__ Kb, const float* __restrict__ rowsum,
        const float* __restrict__ v, float* __restrict__ P) {
    int row = blockIdx.x;
    float ui = u_from_rowsum(rowsum[row]);
    #pragma unroll
    for (int pass = 0; pass < 4; ++pass) {
        int j = pass * 2048 + threadIdx.x * 8;
        short8 kv = *(const short8*)(Kb + (size_t)row * N + j);
        f32x4 v0 = *(const f32x4*)(v + j);
        f32x4 v1 = *(const f32x4*)(v + j + 4);
        f32x4 o0, o1;
        #pragma unroll
        for (int e = 0; e < 4; ++e) {
            o0[e] = ui * bf2f((u16)kv[e])     * v0[e];
            o1[e] = ui * bf2f((u16)kv[e + 4]) * v1[e];
        }
        *(f32x4*)(P + (size_t)row * N + j)     = o0;
        *(f32x4*)(P + (size_t)row * N + j + 4) = o1;
    }
}

// ---------------------------------------------------------------------------
extern "C" void kernel_launch(void* const* d_in, const int* in_sizes, int n_in,
                              void* d_out, int out_size, void* d_ws, size_t ws_size,
                              hipStream_t stream) {
    const float* src = (const float*)d_in[0];
    const float* tgt = (const float*)d_in[1];
    float* P = (float*)d_out;
    char* ws = (char*)d_ws;

    u16* Kb = (u16*)ws;
    size_t off = (size_t)N * N * 2;                       // 128 MB
    float* rowsum = (float*)(ws + off); off += (size_t)N * 4;
    float* v  = (float*)(ws + off); off += (size_t)N * 4;
    float* x2 = (float*)(ws + off); off += (size_t)N * 4;
    float* y2 = (float*)(ws + off); off += (size_t)N * 4;
    float* partial = (float*)(ws + off); off += (size_t)256 * N * 4;   // 8 MB
    u16* Xb = (u16*)(ws + off); off += (size_t)N * D * 2;
    u16* Yb = (u16*)(ws + off); off += (size_t)N * D * 2;

    hipMemsetAsync(rowsum, 0, (size_t)N * 4, stream);     // atomics accumulate
    hipLaunchKernelGGL(prep_kernel,     dim3(4096),  dim3(256), 0, stream, src, tgt, Xb, Yb, x2, y2);
    hipLaunchKernelGGL(gemm_exp_kernel, dim3(4096),  dim3(256), 0, stream, Xb, Yb, x2, y2, Kb, rowsum);
    hipLaunchKernelGGL(col_mv_kernel,   dim3(1024),  dim3(256), 0, stream, Kb, rowsum, partial);
    hipLaunchKernelGGL(reduce_v_kernel, dim3(32),    dim3(256), 0, stream, partial, v);
    hipLaunchKernelGGL(final_kernel,    dim3(8192),  dim3(256), 0, stream, Kb, rowsum, v, P);
}